// Round 6
// baseline (416.788 us; speedup 1.0000x reference)
//
#include <hip/hip_runtime.h>

#define N_NODES 50000
#define N_EDGES 800000
#define F_IN 128
#define HID 64
#define N_GRAPHS 64

#define SCAN_B ((N_NODES + 255) / 256)     // 196 blocks
#define FUSE_B ((N_EDGES + 255) / 256)     // 3125 blocks == (N_NODES+15)/16: covers both roles

// ---------------- degree (int4-vectorized over contiguous dst row) ----------------
__global__ void deg_kernel(const int* __restrict__ ei, int* __restrict__ ideg, int E) {
    int i = blockIdx.x * blockDim.x + threadIdx.x;
    if (i * 4 >= E) return;
    int4 d = ((const int4*)(ei + E))[i];   // dst = ei[1][*], contiguous
    atomicAdd(&ideg[d.x], 1);
    atomicAdd(&ideg[d.y], 1);
    atomicAdd(&ideg[d.z], 1);
    atomicAdd(&ideg[d.w], 1);
}

// ---------------- 3-phase parallel exclusive scan of in-degrees (+ fused dinv) ----------------
__global__ void scan_part(const int* __restrict__ ideg, int* __restrict__ bsum, int n) {
    __shared__ int s[256];
    int t = threadIdx.x;
    int i = blockIdx.x * 256 + t;
    s[t] = (i < n) ? ideg[i] : 0;
    __syncthreads();
    for (int o = 128; o > 0; o >>= 1) {
        if (t < o) s[t] += s[t + o];
        __syncthreads();
    }
    if (t == 0) bsum[blockIdx.x] = s[0];
}

__global__ void scan_base(const int* __restrict__ bsum, int* __restrict__ bbase, int B) {
    __shared__ int s[256];
    int t = threadIdx.x;
    s[t] = (t < B) ? bsum[t] : 0;
    __syncthreads();
    for (int o = 1; o < 256; o <<= 1) {
        int v = (t >= o) ? s[t - o] : 0;
        __syncthreads();
        s[t] += v;
        __syncthreads();
    }
    if (t < B) bbase[t] = (t == 0) ? 0 : s[t - 1];
}

__global__ void scan_final(const int* __restrict__ ideg, const int* __restrict__ bbase,
                           int* __restrict__ offs, int* __restrict__ cur,
                           float* __restrict__ dinv, int n) {
    __shared__ int s[256];
    int t = threadIdx.x;
    int i = blockIdx.x * 256 + t;
    int v = (i < n) ? ideg[i] : 0;
    s[t] = v;
    __syncthreads();
    for (int o = 1; o < 256; o <<= 1) {
        int u = (t >= o) ? s[t - o] : 0;
        __syncthreads();
        s[t] += u;
        __syncthreads();
    }
    int excl = bbase[blockIdx.x] + s[t] - v;   // exclusive prefix
    if (i < n) {
        offs[i] = excl; cur[i] = excl;
        dinv[i] = rsqrtf((float)v + 1.0f);     // fused normalization coeff
    }
    if (i == n - 1) offs[n] = excl + v;        // total == E
}

// ---------------- FUSED (phased): every block fills 256 edges AND matmuls 16 nodes ----------------
// Phase order hides fill's atomic latency + random-line store drain under the matmul:
//   (1) issue edge loads + atomicAdd  (2) stage W/X, matmul (~4000 cyc)  (3) csr[pos] store last.
__global__ void fused_fill_mm1(const int* __restrict__ ei, const float* __restrict__ dinv,
                               int* __restrict__ cur, int2* __restrict__ csr,
                               const float* __restrict__ X, const float* __restrict__ W,
                               float* __restrict__ Y, int n, int E) {
    constexpr int F = F_IN;
    constexpr int S = F + 4;
    __shared__ float sWt[64 * S];          // [feat][k]
    __shared__ float sX[16 * F];           // [node][k]
    int tid = threadIdx.x;

    // ---- phase 1: fill front-end (atomic issued now, store deferred) ----
    int e = blockIdx.x * 256 + tid;
    int esrc = 0, pos = -1; float ew = 0.f;
    if (e < E) {
        esrc = ei[e];
        int d = ei[E + e];
        ew = dinv[esrc];
        pos = atomicAdd(&cur[d], 1);
    }

    // ---- phase 2: matmul Y[16 nodes, 64] = X @ W ----
    for (int j = tid; j < F * 64; j += 256) {
        int k = j >> 6, f = j & 63;        // W is [k][f] row-major
        sWt[f * S + k] = W[j];
    }
    int nodeBase = blockIdx.x * 16;
    for (int i = tid; i < 16 * F; i += 256) {
        int node = nodeBase + i / F;
        sX[i] = (node < n) ? X[(size_t)node * F + (i % F)] : 0.0f;
    }
    __syncthreads();
    int feat = tid & 63;
    int q = tid >> 6;                      // wave id: nodes q*4 .. q*4+3
    const float4* wt = (const float4*)&sWt[feat * S];
    const float4* x0 = (const float4*)&sX[(q * 4 + 0) * F];
    const float4* x1 = (const float4*)&sX[(q * 4 + 1) * F];
    const float4* x2 = (const float4*)&sX[(q * 4 + 2) * F];
    const float4* x3 = (const float4*)&sX[(q * 4 + 3) * F];
    float a0 = 0.f, a1 = 0.f, a2 = 0.f, a3 = 0.f;
#pragma unroll 8
    for (int k4 = 0; k4 < F / 4; ++k4) {
        float4 w = wt[k4];
        float4 v;
        v = x0[k4]; a0 += v.x * w.x + v.y * w.y + v.z * w.z + v.w * w.w;
        v = x1[k4]; a1 += v.x * w.x + v.y * w.y + v.z * w.z + v.w * w.w;
        v = x2[k4]; a2 += v.x * w.x + v.y * w.y + v.z * w.z + v.w * w.w;
        v = x3[k4]; a3 += v.x * w.x + v.y * w.y + v.z * w.z + v.w * w.w;
    }
    int n0 = nodeBase + q * 4;
    if (n0 + 0 < n) Y[(size_t)(n0 + 0) * 64 + feat] = a0;
    if (n0 + 1 < n) Y[(size_t)(n0 + 1) * 64 + feat] = a1;
    if (n0 + 2 < n) Y[(size_t)(n0 + 2) * 64 + feat] = a2;
    if (n0 + 3 < n) Y[(size_t)(n0 + 3) * 64 + feat] = a3;

    // ---- phase 3: deferred CSR store (atomic result long since landed) ----
    if (pos >= 0) csr[pos] = make_int2(esrc, __float_as_int(ew));
}

// ---------------- dense matmul (layers 2,3): Y[n,64] = X[n,64] @ W[64,64] ----------------
template <int F>
__global__ void matmul_kernel(const float* __restrict__ X, const float* __restrict__ W,
                              float* __restrict__ Y, int n) {
    constexpr int S = F + 4;
    __shared__ float sWt[64 * S];
    __shared__ float sX[16 * F];
    int tid = threadIdx.x;
    for (int j = tid; j < F * 64; j += 256) {
        int k = j >> 6, f = j & 63;
        sWt[f * S + k] = W[j];
    }
    int nodeBase = blockIdx.x * 16;
    for (int i = tid; i < 16 * F; i += 256) {
        int node = nodeBase + i / F;
        sX[i] = (node < n) ? X[(size_t)node * F + (i % F)] : 0.0f;
    }
    __syncthreads();
    int feat = tid & 63;
    int q = tid >> 6;
    const float4* wt = (const float4*)&sWt[feat * S];
    const float4* x0 = (const float4*)&sX[(q * 4 + 0) * F];
    const float4* x1 = (const float4*)&sX[(q * 4 + 1) * F];
    const float4* x2 = (const float4*)&sX[(q * 4 + 2) * F];
    const float4* x3 = (const float4*)&sX[(q * 4 + 3) * F];
    float a0 = 0.f, a1 = 0.f, a2 = 0.f, a3 = 0.f;
#pragma unroll 8
    for (int k4 = 0; k4 < F / 4; ++k4) {
        float4 w = wt[k4];
        float4 v;
        v = x0[k4]; a0 += v.x * w.x + v.y * w.y + v.z * w.z + v.w * w.w;
        v = x1[k4]; a1 += v.x * w.x + v.y * w.y + v.z * w.z + v.w * w.w;
        v = x2[k4]; a2 += v.x * w.x + v.y * w.y + v.z * w.z + v.w * w.w;
        v = x3[k4]; a3 += v.x * w.x + v.y * w.y + v.z * w.z + v.w * w.w;
    }
    int n0 = nodeBase + q * 4;
    if (n0 + 0 < n) Y[(size_t)(n0 + 0) * 64 + feat] = a0;
    if (n0 + 1 < n) Y[(size_t)(n0 + 1) * 64 + feat] = a1;
    if (n0 + 2 < n) Y[(size_t)(n0 + 2) * 64 + feat] = a2;
    if (n0 + 3 < n) Y[(size_t)(n0 + 3) * 64 + feat] = a3;
}

// ---------------- fused CSR gather + self-loop + bias + ReLU (unroll 8, phased loads) ----------------
__global__ void agg_kernel(const float* __restrict__ hp, const float* __restrict__ dinv,
                           const int* __restrict__ offs, const int2* __restrict__ csr,
                           const float* __restrict__ b, float* __restrict__ out, int n) {
    int node = blockIdx.x * 4 + (threadIdx.x >> 6);
    int lane = threadIdx.x & 63;
    if (node >= n) return;
    int beg = offs[node], end = offs[node + 1];
    float selfv = hp[(size_t)node * 64 + lane];    // prefetch self term early
    float dn = dinv[node];
    float acc = 0.f;
    int i = beg;
    for (; i + 8 <= end; i += 8) {
        int2 ee[8];
        float vv[8];
#pragma unroll
        for (int j = 0; j < 8; ++j) ee[j] = csr[i + j];
#pragma unroll
        for (int j = 0; j < 8; ++j) vv[j] = hp[(size_t)ee[j].x * 64 + lane];
#pragma unroll
        for (int j = 0; j < 8; ++j) acc += vv[j] * __int_as_float(ee[j].y);
    }
    for (; i < end; ++i) {
        int2 e = csr[i];
        acc += hp[(size_t)e.x * 64 + lane] * __int_as_float(e.y);
    }
    float v = dn * acc + dn * dn * selfv + b[lane];
    out[(size_t)node * 64 + lane] = v > 0.f ? v : 0.f;
}

// ---------------- pooling over sorted batch: sum / count / max ----------------
__global__ void pool_kernel(const float* __restrict__ h1, const float* __restrict__ h2,
                            const float* __restrict__ h3, const int* __restrict__ batch,
                            float* __restrict__ padd, unsigned int* __restrict__ pmax,
                            int* __restrict__ pcnt, int n, int chunk) {
    int f = threadIdx.x;                       // 0..191
    int start = blockIdx.x * chunk;
    int end = min(start + chunk, n);
    if (start >= end) return;
    const float* src = (f < 64) ? h1 : ((f < 128) ? h2 : h3);
    int fo = f & 63;
    float sum = 0.0f, mx = 0.0f;               // features are post-ReLU (>=0)
    int g = batch[start];
    int runStart = start;
    for (int node = start; node < end; ++node) {
        int bg = batch[node];
        if (bg != g) {
            unsafeAtomicAdd(&padd[g * 192 + f], sum);
            atomicMax(&pmax[g * 192 + f], __float_as_uint(mx));
            if (f == 0) atomicAdd(&pcnt[g], node - runStart);
            sum = 0.0f; mx = 0.0f; g = bg; runStart = node;
        }
        float v = src[(size_t)node * 64 + fo];
        sum += v;
        mx = fmaxf(mx, v);
    }
    unsafeAtomicAdd(&padd[g * 192 + f], sum);
    atomicMax(&pmax[g * 192 + f], __float_as_uint(mx));
    if (f == 0) atomicAdd(&pcnt[g], end - runStart);
}

// ---------------- per-graph MLP + log_softmax ----------------
__global__ void mlp_kernel(const float* __restrict__ padd, const unsigned int* __restrict__ pmax,
                           const int* __restrict__ pcnt,
                           const float* __restrict__ lin1_W, const float* __restrict__ lin1_b,
                           const float* __restrict__ lin2_W, const float* __restrict__ lin2_b,
                           float* __restrict__ out) {
    int g = blockIdx.x;     // 64 blocks x 64 threads
    int t = threadIdx.x;
    __shared__ float gv[576];
    __shared__ float hid[64];
    float cnt = (float)pcnt[g];
    for (int i = t; i < 192; i += 64) {
        float a = padd[g * 192 + i];
        gv[i] = a;                                   // add
        gv[192 + i] = a / cnt;                       // mean
        gv[384 + i] = __uint_as_float(pmax[g * 192 + i]);  // max
    }
    __syncthreads();
    float acc = lin1_b[t];
#pragma unroll 8
    for (int k = 0; k < 576; ++k) acc += gv[k] * lin1_W[k * 64 + t];
    hid[t] = acc > 0.0f ? acc : 0.0f;
    __syncthreads();
    if (t == 0) {
        float l0 = lin2_b[0], l1 = lin2_b[1];
        for (int k = 0; k < 64; ++k) {
            l0 += hid[k] * lin2_W[k * 2 + 0];
            l1 += hid[k] * lin2_W[k * 2 + 1];
        }
        float m = fmaxf(l0, l1);
        float lse = m + logf(expf(l0 - m) + expf(l1 - m));
        out[g * 2 + 0] = l0 - lse;
        out[g * 2 + 1] = l1 - lse;
    }
}

extern "C" void kernel_launch(void* const* d_in, const int* in_sizes, int n_in,
                              void* d_out, int out_size, void* d_ws, size_t ws_size,
                              hipStream_t stream) {
    const float* x      = (const float*)d_in[0];
    const float* W1     = (const float*)d_in[1];
    const float* b1     = (const float*)d_in[2];
    const float* W2     = (const float*)d_in[3];
    const float* b2     = (const float*)d_in[4];
    const float* W3     = (const float*)d_in[5];
    const float* b3     = (const float*)d_in[6];
    const float* lin1_W = (const float*)d_in[7];
    const float* lin1_b = (const float*)d_in[8];
    const float* lin2_W = (const float*)d_in[9];
    const float* lin2_b = (const float*)d_in[10];
    const int*   ei     = (const int*)d_in[11];
    const int*   batch  = (const int*)d_in[12];
    float* out = (float*)d_out;

    char* ws = (char*)d_ws;
    size_t off = 0;
    auto alloc = [&](size_t bytes) {
        void* p = ws + off;
        off = (off + bytes + 255) & ~(size_t)255;
        return p;
    };
    int*   ideg    = (int*)  alloc(N_NODES * 4);
    float* dinv    = (float*)alloc(N_NODES * 4);
    int*   offs    = (int*)  alloc((N_NODES + 1) * 4);
    int*   cur     = (int*)  alloc(N_NODES * 4);
    int*   bsum    = (int*)  alloc(SCAN_B * 4);
    int*   bbase   = (int*)  alloc(SCAN_B * 4);
    int2*  csr     = (int2*) alloc((size_t)N_EDGES * 8);
    float* hp      = (float*)alloc((size_t)N_NODES * 64 * 4);
    float* h1      = (float*)alloc((size_t)N_NODES * 64 * 4);
    float* h2      = (float*)alloc((size_t)N_NODES * 64 * 4);
    float* h3      = (float*)alloc((size_t)N_NODES * 64 * 4);
    float* padd    = (float*)alloc(N_GRAPHS * 192 * 4);
    unsigned int* pmax = (unsigned int*)alloc(N_GRAPHS * 192 * 4);
    int*   pcnt    = (int*) alloc(N_GRAPHS * 4);

    // normalization + CSR offsets (fill fused with matmul1 below)
    hipMemsetAsync(ideg, 0, N_NODES * 4, stream);
    deg_kernel<<<(N_EDGES / 4 + 255) / 256, 256, 0, stream>>>(ei, ideg, N_EDGES);
    scan_part <<<SCAN_B, 256, 0, stream>>>(ideg, bsum, N_NODES);
    scan_base <<<1, 256, 0, stream>>>(bsum, bbase, SCAN_B);
    scan_final<<<SCAN_B, 256, 0, stream>>>(ideg, bbase, offs, cur, dinv, N_NODES);

    const int mmGrid  = (N_NODES + 15) / 16;
    const int aggGrid = (N_NODES + 3) / 4;

    // layer 1 (every block: fill 256 edges + matmul 16 nodes, phased)
    fused_fill_mm1<<<FUSE_B, 256, 0, stream>>>(ei, dinv, cur, csr, x, W1, hp, N_NODES, N_EDGES);
    agg_kernel<<<aggGrid, 256, 0, stream>>>(hp, dinv, offs, csr, b1, h1, N_NODES);
    // layer 2
    matmul_kernel<HID><<<mmGrid, 256, 0, stream>>>(h1, W2, hp, N_NODES);
    agg_kernel<<<aggGrid, 256, 0, stream>>>(hp, dinv, offs, csr, b2, h2, N_NODES);
    // layer 3
    matmul_kernel<HID><<<mmGrid, 256, 0, stream>>>(h2, W3, hp, N_NODES);
    agg_kernel<<<aggGrid, 256, 0, stream>>>(hp, dinv, offs, csr, b3, h3, N_NODES);

    // pooling
    hipMemsetAsync(padd, 0, N_GRAPHS * 192 * 4, stream);
    hipMemsetAsync(pmax, 0, N_GRAPHS * 192 * 4, stream);
    hipMemsetAsync(pcnt, 0, N_GRAPHS * 4, stream);
    const int chunk = (N_NODES + 511) / 512;           // 98 nodes/block
    pool_kernel<<<512, 192, 0, stream>>>(h1, h2, h3, batch, padd, pmax, pcnt, N_NODES, chunk);

    // head MLP + log_softmax
    mlp_kernel<<<N_GRAPHS, 64, 0, stream>>>(padd, pmax, pcnt, lin1_W, lin1_b, lin2_W, lin2_b, out);
}

// Round 7
// 403.639 us; speedup vs baseline: 1.0326x; 1.0326x over previous
//
#include <hip/hip_runtime.h>
#include <hip/hip_fp16.h>

#define N_NODES 50000
#define N_EDGES 800000
#define F_IN 128
#define HID 64
#define N_GRAPHS 64

#define SCAN_B ((N_NODES + 255) / 256)     // 196 blocks
#define FUSE_B ((N_EDGES + 255) / 256)     // 3125 blocks == (N_NODES+15)/16: covers both roles

// ---------------- degree (int4-vectorized over contiguous dst row) ----------------
__global__ void deg_kernel(const int* __restrict__ ei, int* __restrict__ ideg, int E) {
    int i = blockIdx.x * blockDim.x + threadIdx.x;
    if (i * 4 >= E) return;
    int4 d = ((const int4*)(ei + E))[i];   // dst = ei[1][*], contiguous
    atomicAdd(&ideg[d.x], 1);
    atomicAdd(&ideg[d.y], 1);
    atomicAdd(&ideg[d.z], 1);
    atomicAdd(&ideg[d.w], 1);
}

// ---------------- 3-phase parallel exclusive scan of in-degrees (+ fused dinv) ----------------
__global__ void scan_part(const int* __restrict__ ideg, int* __restrict__ bsum, int n) {
    __shared__ int s[256];
    int t = threadIdx.x;
    int i = blockIdx.x * 256 + t;
    s[t] = (i < n) ? ideg[i] : 0;
    __syncthreads();
    for (int o = 128; o > 0; o >>= 1) {
        if (t < o) s[t] += s[t + o];
        __syncthreads();
    }
    if (t == 0) bsum[blockIdx.x] = s[0];
}

__global__ void scan_base(const int* __restrict__ bsum, int* __restrict__ bbase, int B) {
    __shared__ int s[256];
    int t = threadIdx.x;
    s[t] = (t < B) ? bsum[t] : 0;
    __syncthreads();
    for (int o = 1; o < 256; o <<= 1) {
        int v = (t >= o) ? s[t - o] : 0;
        __syncthreads();
        s[t] += v;
        __syncthreads();
    }
    if (t < B) bbase[t] = (t == 0) ? 0 : s[t - 1];
}

__global__ void scan_final(const int* __restrict__ ideg, const int* __restrict__ bbase,
                           int* __restrict__ offs, int* __restrict__ cur,
                           float* __restrict__ dinv, int n) {
    __shared__ int s[256];
    int t = threadIdx.x;
    int i = blockIdx.x * 256 + t;
    int v = (i < n) ? ideg[i] : 0;
    s[t] = v;
    __syncthreads();
    for (int o = 1; o < 256; o <<= 1) {
        int u = (t >= o) ? s[t - o] : 0;
        __syncthreads();
        s[t] += u;
        __syncthreads();
    }
    int excl = bbase[blockIdx.x] + s[t] - v;   // exclusive prefix
    if (i < n) {
        offs[i] = excl; cur[i] = excl;
        dinv[i] = rsqrtf((float)v + 1.0f);     // fused normalization coeff
    }
    if (i == n - 1) offs[n] = excl + v;        // total == E
}

// ---------------- FUSED (phased): every block fills 256 edges AND matmuls 16 nodes ----------------
// Also writes an fp16 copy of Y (hp16) for the cache-BW-bound neighbor gather in agg.
__global__ void fused_fill_mm1(const int* __restrict__ ei, const float* __restrict__ dinv,
                               int* __restrict__ cur, int2* __restrict__ csr,
                               const float* __restrict__ X, const float* __restrict__ W,
                               float* __restrict__ Y, __half* __restrict__ Y16,
                               int n, int E) {
    constexpr int F = F_IN;
    constexpr int S = F + 4;
    __shared__ float sWt[64 * S];          // [feat][k]
    __shared__ float sX[16 * F];           // [node][k]
    int tid = threadIdx.x;

    // ---- phase 1: fill front-end (atomic issued now, store deferred) ----
    int e = blockIdx.x * 256 + tid;
    int esrc = 0, pos = -1; float ew = 0.f;
    if (e < E) {
        esrc = ei[e];
        int d = ei[E + e];
        ew = dinv[esrc];
        pos = atomicAdd(&cur[d], 1);
    }

    // ---- phase 2: matmul Y[16 nodes, 64] = X @ W ----
    for (int j = tid; j < F * 64; j += 256) {
        int k = j >> 6, f = j & 63;        // W is [k][f] row-major
        sWt[f * S + k] = W[j];
    }
    int nodeBase = blockIdx.x * 16;
    for (int i = tid; i < 16 * F; i += 256) {
        int node = nodeBase + i / F;
        sX[i] = (node < n) ? X[(size_t)node * F + (i % F)] : 0.0f;
    }
    __syncthreads();
    int feat = tid & 63;
    int q = tid >> 6;                      // wave id: nodes q*4 .. q*4+3
    const float4* wt = (const float4*)&sWt[feat * S];
    const float4* x0 = (const float4*)&sX[(q * 4 + 0) * F];
    const float4* x1 = (const float4*)&sX[(q * 4 + 1) * F];
    const float4* x2 = (const float4*)&sX[(q * 4 + 2) * F];
    const float4* x3 = (const float4*)&sX[(q * 4 + 3) * F];
    float a0 = 0.f, a1 = 0.f, a2 = 0.f, a3 = 0.f;
#pragma unroll 8
    for (int k4 = 0; k4 < F / 4; ++k4) {
        float4 w = wt[k4];
        float4 v;
        v = x0[k4]; a0 += v.x * w.x + v.y * w.y + v.z * w.z + v.w * w.w;
        v = x1[k4]; a1 += v.x * w.x + v.y * w.y + v.z * w.z + v.w * w.w;
        v = x2[k4]; a2 += v.x * w.x + v.y * w.y + v.z * w.z + v.w * w.w;
        v = x3[k4]; a3 += v.x * w.x + v.y * w.y + v.z * w.z + v.w * w.w;
    }
    int n0 = nodeBase + q * 4;
    if (n0 + 0 < n) { Y[(size_t)(n0 + 0) * 64 + feat] = a0; Y16[(size_t)(n0 + 0) * 64 + feat] = __float2half(a0); }
    if (n0 + 1 < n) { Y[(size_t)(n0 + 1) * 64 + feat] = a1; Y16[(size_t)(n0 + 1) * 64 + feat] = __float2half(a1); }
    if (n0 + 2 < n) { Y[(size_t)(n0 + 2) * 64 + feat] = a2; Y16[(size_t)(n0 + 2) * 64 + feat] = __float2half(a2); }
    if (n0 + 3 < n) { Y[(size_t)(n0 + 3) * 64 + feat] = a3; Y16[(size_t)(n0 + 3) * 64 + feat] = __float2half(a3); }

    // ---- phase 3: deferred CSR store (atomic result long since landed) ----
    if (pos >= 0) csr[pos] = make_int2(esrc, __float_as_int(ew));
}

// ---------------- dense matmul (layers 2,3): fp32 out + fp16 gather copy ----------------
template <int F>
__global__ void matmul_kernel(const float* __restrict__ X, const float* __restrict__ W,
                              float* __restrict__ Y, __half* __restrict__ Y16, int n) {
    constexpr int S = F + 4;
    __shared__ float sWt[64 * S];
    __shared__ float sX[16 * F];
    int tid = threadIdx.x;
    for (int j = tid; j < F * 64; j += 256) {
        int k = j >> 6, f = j & 63;
        sWt[f * S + k] = W[j];
    }
    int nodeBase = blockIdx.x * 16;
    for (int i = tid; i < 16 * F; i += 256) {
        int node = nodeBase + i / F;
        sX[i] = (node < n) ? X[(size_t)node * F + (i % F)] : 0.0f;
    }
    __syncthreads();
    int feat = tid & 63;
    int q = tid >> 6;
    const float4* wt = (const float4*)&sWt[feat * S];
    const float4* x0 = (const float4*)&sX[(q * 4 + 0) * F];
    const float4* x1 = (const float4*)&sX[(q * 4 + 1) * F];
    const float4* x2 = (const float4*)&sX[(q * 4 + 2) * F];
    const float4* x3 = (const float4*)&sX[(q * 4 + 3) * F];
    float a0 = 0.f, a1 = 0.f, a2 = 0.f, a3 = 0.f;
#pragma unroll 8
    for (int k4 = 0; k4 < F / 4; ++k4) {
        float4 w = wt[k4];
        float4 v;
        v = x0[k4]; a0 += v.x * w.x + v.y * w.y + v.z * w.z + v.w * w.w;
        v = x1[k4]; a1 += v.x * w.x + v.y * w.y + v.z * w.z + v.w * w.w;
        v = x2[k4]; a2 += v.x * w.x + v.y * w.y + v.z * w.z + v.w * w.w;
        v = x3[k4]; a3 += v.x * w.x + v.y * w.y + v.z * w.z + v.w * w.w;
    }
    int n0 = nodeBase + q * 4;
    if (n0 + 0 < n) { Y[(size_t)(n0 + 0) * 64 + feat] = a0; Y16[(size_t)(n0 + 0) * 64 + feat] = __float2half(a0); }
    if (n0 + 1 < n) { Y[(size_t)(n0 + 1) * 64 + feat] = a1; Y16[(size_t)(n0 + 1) * 64 + feat] = __float2half(a1); }
    if (n0 + 2 < n) { Y[(size_t)(n0 + 2) * 64 + feat] = a2; Y16[(size_t)(n0 + 2) * 64 + feat] = __float2half(a2); }
    if (n0 + 3 < n) { Y[(size_t)(n0 + 3) * 64 + feat] = a3; Y16[(size_t)(n0 + 3) * 64 + feat] = __float2half(a3); }
}

// ---------------- fused CSR gather (fp16 rows) + self-loop(fp32) + bias + ReLU ----------------
__global__ void agg_kernel(const float* __restrict__ hp, const __half* __restrict__ hp16,
                           const float* __restrict__ dinv,
                           const int* __restrict__ offs, const int2* __restrict__ csr,
                           const float* __restrict__ b, float* __restrict__ out, int n) {
    int node = blockIdx.x * 4 + (threadIdx.x >> 6);
    int lane = threadIdx.x & 63;
    if (node >= n) return;
    int beg = offs[node], end = offs[node + 1];
    float selfv = hp[(size_t)node * 64 + lane];    // self term in fp32
    float dn = dinv[node];
    float acc = 0.f;
    int i = beg;
    for (; i + 8 <= end; i += 8) {
        int2 ee[8];
        float vv[8];
#pragma unroll
        for (int j = 0; j < 8; ++j) ee[j] = csr[i + j];
#pragma unroll
        for (int j = 0; j < 8; ++j) vv[j] = __half2float(hp16[(size_t)ee[j].x * 64 + lane]);
#pragma unroll
        for (int j = 0; j < 8; ++j) acc += vv[j] * __int_as_float(ee[j].y);
    }
    for (; i < end; ++i) {
        int2 e = csr[i];
        acc += __half2float(hp16[(size_t)e.x * 64 + lane]) * __int_as_float(e.y);
    }
    float v = dn * acc + dn * dn * selfv + b[lane];
    out[(size_t)node * 64 + lane] = v > 0.f ? v : 0.f;
}

// ---------------- pooling over sorted batch: sum / count / max ----------------
__global__ void pool_kernel(const float* __restrict__ h1, const float* __restrict__ h2,
                            const float* __restrict__ h3, const int* __restrict__ batch,
                            float* __restrict__ padd, unsigned int* __restrict__ pmax,
                            int* __restrict__ pcnt, int n, int chunk) {
    int f = threadIdx.x;                       // 0..191
    int start = blockIdx.x * chunk;
    int end = min(start + chunk, n);
    if (start >= end) return;
    const float* src = (f < 64) ? h1 : ((f < 128) ? h2 : h3);
    int fo = f & 63;
    float sum = 0.0f, mx = 0.0f;               // features are post-ReLU (>=0)
    int g = batch[start];
    int runStart = start;
    for (int node = start; node < end; ++node) {
        int bg = batch[node];
        if (bg != g) {
            unsafeAtomicAdd(&padd[g * 192 + f], sum);
            atomicMax(&pmax[g * 192 + f], __float_as_uint(mx));
            if (f == 0) atomicAdd(&pcnt[g], node - runStart);
            sum = 0.0f; mx = 0.0f; g = bg; runStart = node;
        }
        float v = src[(size_t)node * 64 + fo];
        sum += v;
        mx = fmaxf(mx, v);
    }
    unsafeAtomicAdd(&padd[g * 192 + f], sum);
    atomicMax(&pmax[g * 192 + f], __float_as_uint(mx));
    if (f == 0) atomicAdd(&pcnt[g], end - runStart);
}

// ---------------- per-graph MLP + log_softmax ----------------
__global__ void mlp_kernel(const float* __restrict__ padd, const unsigned int* __restrict__ pmax,
                           const int* __restrict__ pcnt,
                           const float* __restrict__ lin1_W, const float* __restrict__ lin1_b,
                           const float* __restrict__ lin2_W, const float* __restrict__ lin2_b,
                           float* __restrict__ out) {
    int g = blockIdx.x;     // 64 blocks x 64 threads
    int t = threadIdx.x;
    __shared__ float gv[576];
    __shared__ float hid[64];
    float cnt = (float)pcnt[g];
    for (int i = t; i < 192; i += 64) {
        float a = padd[g * 192 + i];
        gv[i] = a;                                   // add
        gv[192 + i] = a / cnt;                       // mean
        gv[384 + i] = __uint_as_float(pmax[g * 192 + i]);  // max
    }
    __syncthreads();
    float acc = lin1_b[t];
#pragma unroll 8
    for (int k = 0; k < 576; ++k) acc += gv[k] * lin1_W[k * 64 + t];
    hid[t] = acc > 0.0f ? acc : 0.0f;
    __syncthreads();
    if (t == 0) {
        float l0 = lin2_b[0], l1 = lin2_b[1];
        for (int k = 0; k < 64; ++k) {
            l0 += hid[k] * lin2_W[k * 2 + 0];
            l1 += hid[k] * lin2_W[k * 2 + 1];
        }
        float m = fmaxf(l0, l1);
        float lse = m + logf(expf(l0 - m) + expf(l1 - m));
        out[g * 2 + 0] = l0 - lse;
        out[g * 2 + 1] = l1 - lse;
    }
}

extern "C" void kernel_launch(void* const* d_in, const int* in_sizes, int n_in,
                              void* d_out, int out_size, void* d_ws, size_t ws_size,
                              hipStream_t stream) {
    const float* x      = (const float*)d_in[0];
    const float* W1     = (const float*)d_in[1];
    const float* b1     = (const float*)d_in[2];
    const float* W2     = (const float*)d_in[3];
    const float* b2     = (const float*)d_in[4];
    const float* W3     = (const float*)d_in[5];
    const float* b3     = (const float*)d_in[6];
    const float* lin1_W = (const float*)d_in[7];
    const float* lin1_b = (const float*)d_in[8];
    const float* lin2_W = (const float*)d_in[9];
    const float* lin2_b = (const float*)d_in[10];
    const int*   ei     = (const int*)d_in[11];
    const int*   batch  = (const int*)d_in[12];
    float* out = (float*)d_out;

    char* ws = (char*)d_ws;
    size_t off = 0;
    auto alloc = [&](size_t bytes) {
        void* p = ws + off;
        off = (off + bytes + 255) & ~(size_t)255;
        return p;
    };
    int*   ideg    = (int*)  alloc(N_NODES * 4);
    float* dinv    = (float*)alloc(N_NODES * 4);
    int*   offs    = (int*)  alloc((N_NODES + 1) * 4);
    int*   cur     = (int*)  alloc(N_NODES * 4);
    int*   bsum    = (int*)  alloc(SCAN_B * 4);
    int*   bbase   = (int*)  alloc(SCAN_B * 4);
    int2*  csr     = (int2*) alloc((size_t)N_EDGES * 8);
    float* hp      = (float*)alloc((size_t)N_NODES * 64 * 4);
    __half* hp16   = (__half*)alloc((size_t)N_NODES * 64 * 2);
    float* h1      = (float*)alloc((size_t)N_NODES * 64 * 4);
    float* h2      = (float*)alloc((size_t)N_NODES * 64 * 4);
    float* h3      = (float*)alloc((size_t)N_NODES * 64 * 4);
    float* padd    = (float*)alloc(N_GRAPHS * 192 * 4);
    unsigned int* pmax = (unsigned int*)alloc(N_GRAPHS * 192 * 4);
    int*   pcnt    = (int*) alloc(N_GRAPHS * 4);

    // normalization + CSR offsets (fill fused with matmul1 below)
    hipMemsetAsync(ideg, 0, N_NODES * 4, stream);
    deg_kernel<<<(N_EDGES / 4 + 255) / 256, 256, 0, stream>>>(ei, ideg, N_EDGES);
    scan_part <<<SCAN_B, 256, 0, stream>>>(ideg, bsum, N_NODES);
    scan_base <<<1, 256, 0, stream>>>(bsum, bbase, SCAN_B);
    scan_final<<<SCAN_B, 256, 0, stream>>>(ideg, bbase, offs, cur, dinv, N_NODES);

    const int mmGrid  = (N_NODES + 15) / 16;
    const int aggGrid = (N_NODES + 3) / 4;

    // layer 1 (every block: fill 256 edges + matmul 16 nodes, phased)
    fused_fill_mm1<<<FUSE_B, 256, 0, stream>>>(ei, dinv, cur, csr, x, W1, hp, hp16,
                                               N_NODES, N_EDGES);
    agg_kernel<<<aggGrid, 256, 0, stream>>>(hp, hp16, dinv, offs, csr, b1, h1, N_NODES);
    // layer 2
    matmul_kernel<HID><<<mmGrid, 256, 0, stream>>>(h1, W2, hp, hp16, N_NODES);
    agg_kernel<<<aggGrid, 256, 0, stream>>>(hp, hp16, dinv, offs, csr, b2, h2, N_NODES);
    // layer 3
    matmul_kernel<HID><<<mmGrid, 256, 0, stream>>>(h2, W3, hp, hp16, N_NODES);
    agg_kernel<<<aggGrid, 256, 0, stream>>>(hp, hp16, dinv, offs, csr, b3, h3, N_NODES);

    // pooling
    hipMemsetAsync(padd, 0, N_GRAPHS * 192 * 4, stream);
    hipMemsetAsync(pmax, 0, N_GRAPHS * 192 * 4, stream);
    hipMemsetAsync(pcnt, 0, N_GRAPHS * 4, stream);
    const int chunk = (N_NODES + 511) / 512;           // 98 nodes/block
    pool_kernel<<<512, 192, 0, stream>>>(h1, h2, h3, batch, padd, pmax, pcnt, N_NODES, chunk);

    // head MLP + log_softmax
    mlp_kernel<<<N_GRAPHS, 64, 0, stream>>>(padd, pmax, pcnt, lin1_W, lin1_b, lin2_W, lin2_b, out);
}